// Round 6
// baseline (173.659 us; speedup 1.0000x reference)
//
#include <hip/hip_runtime.h>
#include <hip/hip_bf16.h>

typedef __attribute__((ext_vector_type(8))) short short8;
typedef __attribute__((ext_vector_type(4))) float f32x4;
typedef __attribute__((ext_vector_type(4))) _Float16 half4;
typedef __attribute__((ext_vector_type(8))) _Float16 half8;

#define NB 4
#define NN 9216
#define NM 2304
#define MSPLIT 2
#define MSL (NM / MSPLIT)   // 1152

__device__ inline unsigned pk2(float a, float b) {
  __hip_bfloat16 ha = __float2bfloat16(a), hb = __float2bfloat16(b);
  return (unsigned)*(unsigned short*)&ha | ((unsigned)*(unsigned short*)&hb << 16);
}
__device__ inline float b2f(short s) {
  unsigned u = ((unsigned)(unsigned short)s) << 16; return *(float*)&u;
}
__device__ inline short8 pack8(const float* v) {
  short8 s;
#pragma unroll
  for (int j = 0; j < 8; ++j) { __hip_bfloat16 h = __float2bfloat16(v[j]); s[j] = *(short*)&h; }
  return s;
}
__device__ inline short8 ldw8(const float* p) {
  float tmp[8];
  *(float4*)&tmp[0] = *(const float4*)p;
  *(float4*)&tmp[4] = *(const float4*)(p + 4);
  return pack8(tmp);
}

// ---------------------------------------------------------------------------
// Fused conv1x1 (theta,g,phi) + 2x2 maxpool for g/phi.  (r5 structure, verified)
// grid (288, B) x 256; wave owns one 16-wide ot slice.  Gcm now f16.
// ---------------------------------------------------------------------------
__global__ __launch_bounds__(256) void conv_pool_k(
    const float* __restrict__ x, const float* __restrict__ feat,
    const float* __restrict__ tw, const float* __restrict__ tbi,
    const float* __restrict__ gw, const float* __restrict__ gbi,
    const float* __restrict__ pw, const float* __restrict__ pbi,
    __hip_bfloat16* __restrict__ Theta, _Float16* __restrict__ Gcm,
    __hip_bfloat16* __restrict__ PhiT, float* __restrict__ psum) {
  int t = threadIdx.x, wv = t >> 6, lane = t & 63, l15 = lane & 15, q = lane >> 4;
  int b = blockIdx.y, bx = blockIdx.x;
  if (bx == 0 && b == 0 && t < 64) psum[t] = 0.f;
  int jt = bx % 6, rp = bx / 6;
  int i0 = rp * 2, j0 = jt * 16;
  int ntop = i0 * 96 + j0;
  int ot = wv;

  short8 wt[2], wg[2], wp1;
#pragma unroll
  for (int kf = 0; kf < 2; ++kf) {
    wt[kf] = ldw8(tw + (size_t)(ot * 16 + l15) * 64 + kf * 32 + q * 8);
    wg[kf] = ldw8(gw + (size_t)(ot * 16 + l15) * 64 + kf * 32 + q * 8);
  }
  wp1 = ldw8(pw + (size_t)(ot * 16 + l15) * 32 + q * 8);

  short8 bxf[2][2], bff[2];
  {
    float tmp[8];
#pragma unroll
    for (int row = 0; row < 2; ++row) {
#pragma unroll
      for (int kf = 0; kf < 2; ++kf) {
#pragma unroll
        for (int j = 0; j < 8; ++j)
          tmp[j] = x[((size_t)b * 64 + kf * 32 + q * 8 + j) * NN + ntop + row * 96 + l15];
        bxf[row][kf] = pack8(tmp);
      }
#pragma unroll
      for (int j = 0; j < 8; ++j)
        tmp[j] = feat[((size_t)b * 32 + q * 8 + j) * NN + ntop + row * 96 + l15];
      bff[row] = pack8(tmp);
    }
  }

  int m = rp * 48 + ((j0 + l15) >> 1);
  bool em = (l15 & 1) == 0;

#pragma unroll
  for (int row = 0; row < 2; ++row) {
    f32x4 d;
#pragma unroll
    for (int r = 0; r < 4; ++r) d[r] = tbi[ot * 16 + q * 4 + r];
    d = __builtin_amdgcn_mfma_f32_16x16x32_bf16(wt[0], bxf[row][0], d, 0, 0, 0);
    d = __builtin_amdgcn_mfma_f32_16x16x32_bf16(wt[1], bxf[row][1], d, 0, 0, 0);
    size_t base = ((size_t)b * NN + ntop + row * 96 + l15) * 64 + ot * 16 + q * 4;
    *(unsigned*)(Theta + base) = pk2(d[0], d[1]);
    *(unsigned*)(Theta + base + 2) = pk2(d[2], d[3]);
  }
  {
    f32x4 d0, d1;
#pragma unroll
    for (int r = 0; r < 4; ++r) { float bb = gbi[ot * 16 + q * 4 + r]; d0[r] = bb; d1[r] = bb; }
    d0 = __builtin_amdgcn_mfma_f32_16x16x32_bf16(wg[0], bxf[0][0], d0, 0, 0, 0);
    d0 = __builtin_amdgcn_mfma_f32_16x16x32_bf16(wg[1], bxf[0][1], d0, 0, 0, 0);
    d1 = __builtin_amdgcn_mfma_f32_16x16x32_bf16(wg[0], bxf[1][0], d1, 0, 0, 0);
    d1 = __builtin_amdgcn_mfma_f32_16x16x32_bf16(wg[1], bxf[1][1], d1, 0, 0, 0);
    float h[4];
#pragma unroll
    for (int r = 0; r < 4; ++r) {
      float v = fmaxf(d0[r], d1[r]);
      h[r] = fmaxf(v, __shfl_xor(v, 1));
    }
    if (em) {
#pragma unroll
      for (int r = 0; r < 4; ++r)
        Gcm[((size_t)b * 64 + ot * 16 + q * 4 + r) * NM + m] = (_Float16)h[r];
    }
  }
  {
    f32x4 d0, d1;
#pragma unroll
    for (int r = 0; r < 4; ++r) { float bb = pbi[ot * 16 + q * 4 + r]; d0[r] = bb; d1[r] = bb; }
    d0 = __builtin_amdgcn_mfma_f32_16x16x32_bf16(wp1, bff[0], d0, 0, 0, 0);
    d1 = __builtin_amdgcn_mfma_f32_16x16x32_bf16(wp1, bff[1], d1, 0, 0, 0);
    float h[4];
#pragma unroll
    for (int r = 0; r < 4; ++r) {
      float v = fmaxf(d0[r], d1[r]);
      h[r] = fmaxf(v, __shfl_xor(v, 1));
    }
    if (em) {
      size_t base = ((size_t)b * NM + m) * 64 + ot * 16 + q * 4;
      *(unsigned*)(PhiT + base) = pk2(h[0], h[1]);
      *(unsigned*)(PhiT + base + 2) = pk2(h[2], h[3]);
    }
  }
}

// ---------------------------------------------------------------------------
// Attention partial, P-in-register variant.
// grid (144*MSPLIT, B), block 128 (2 waves x 32 n-rows).
// S^T = Phi·Theta^T via 16x16x32 bf16 (D: row m=q*4+r, col n=l15), then
// PV via 16x16x16 f16: A-frag = exp(S^T) IN-LANE (A[row=l15][k=q*4+j]),
// B-frag = G (f16) from gs2, interleaved so one b128 read = both K=16 frags.
// ---------------------------------------------------------------------------
__global__ __launch_bounds__(128) void attn_part(
    const __hip_bfloat16* __restrict__ Theta, const __hip_bfloat16* __restrict__ PhiT,
    const _Float16* __restrict__ Gcm,
    __hip_bfloat16* __restrict__ ypart, float* __restrict__ rsumpart) {
  __shared__ __align__(16) __hip_bfloat16 phis[32][72];  // [m][c]
  __shared__ __align__(16) _Float16 gs2[64][40];         // [c][m-interleaved]

  int t = threadIdx.x, wv = t >> 6, lane = t & 63;
  int l15 = lane & 15, q = lane >> 4;
  int bx = blockIdx.x;
  int nb = bx % 144, split = bx / 144;
  int b = blockIdx.y;
  int n0 = nb * 64, nw = n0 + wv * 32;
  int mbase = split * MSL;

  // Theta B-frags (held): B[k=c=kf*32+q*8+j][n=l15], rows nw+nt*16+l15
  short8 tb[2][2];
#pragma unroll
  for (int nt = 0; nt < 2; ++nt)
#pragma unroll
    for (int kf = 0; kf < 2; ++kf)
      tb[nt][kf] = *(const short8*)(Theta + ((size_t)b * NN + nw + nt * 16 + l15) * 64 + kf * 32 + q * 8);

  f32x4 acc[2][4];
#pragma unroll
  for (int nt = 0; nt < 2; ++nt)
#pragma unroll
    for (int ct = 0; ct < 4; ++ct) acc[nt][ct] = (f32x4){0.f, 0.f, 0.f, 0.f};
  float rsum[2] = {0.f, 0.f};

  const __hip_bfloat16* phibase = PhiT + (size_t)b * NM * 64;
  const _Float16* gbase = Gcm + (size_t)b * 64 * NM;

  for (int ck = 0; ck < MSL / 32; ++ck) {   // 36 chunks
    int m0 = mbase + ck * 32;
    __syncthreads();
#pragma unroll
    for (int p = 0; p < 2; ++p) {  // stage Phi: 32 m x 64 c
      int idx = p * 128 + t, r = idx >> 3, seg = idx & 7;
      *(uint4*)&phis[r][seg * 8] = *(const uint4*)(phibase + (size_t)(m0 + r) * 64 + seg * 8);
    }
#pragma unroll
    for (int p = 0; p < 2; ++p) {  // stage G interleaved: gs2[c][qq*8+{0..3,4..7}] = G[m0+qq*4+{j, 16+j}][c]
      int idx = p * 128 + t, c = idx >> 2, qq = idx & 3;
      const _Float16* gc = gbase + (size_t)c * NM + m0 + qq * 4;
      uint2 lo = *(const uint2*)gc;
      uint2 hi = *(const uint2*)(gc + 16);
      uint4 w; w.x = lo.x; w.y = lo.y; w.z = hi.x; w.w = hi.y;
      *(uint4*)&gs2[c][qq * 8] = w;
    }
    __syncthreads();

    // Phi A-frags: A[m=tm*16+l15][k=c=kf*32+q*8+j]  (shared across nt)
    short8 pha[2][2];
#pragma unroll
    for (int tm = 0; tm < 2; ++tm)
#pragma unroll
      for (int kf = 0; kf < 2; ++kf)
        pha[tm][kf] = *(const short8*)&phis[tm * 16 + l15][kf * 32 + q * 8];
    // G B-frags: elements 0..3 = tm0 (k=q*4+j), 4..7 = tm1
    half8 gv[4];
#pragma unroll
    for (int ct = 0; ct < 4; ++ct)
      gv[ct] = *(const half8*)&gs2[ct * 16 + l15][q * 8];

#pragma unroll
    for (int nt = 0; nt < 2; ++nt) {
      f32x4 s0 = (f32x4){0.f, 0.f, 0.f, 0.f};
      s0 = __builtin_amdgcn_mfma_f32_16x16x32_bf16(pha[0][0], tb[nt][0], s0, 0, 0, 0);
      s0 = __builtin_amdgcn_mfma_f32_16x16x32_bf16(pha[0][1], tb[nt][1], s0, 0, 0, 0);
      f32x4 s1 = (f32x4){0.f, 0.f, 0.f, 0.f};
      s1 = __builtin_amdgcn_mfma_f32_16x16x32_bf16(pha[1][0], tb[nt][0], s1, 0, 0, 0);
      s1 = __builtin_amdgcn_mfma_f32_16x16x32_bf16(pha[1][1], tb[nt][1], s1, 0, 0, 0);

      float e0 = __expf(s0[0]), e1 = __expf(s0[1]), e2 = __expf(s0[2]), e3 = __expf(s0[3]);
      float f0 = __expf(s1[0]), f1 = __expf(s1[1]), f2 = __expf(s1[2]), f3 = __expf(s1[3]);
      rsum[nt] += ((e0 + e1) + (e2 + e3)) + ((f0 + f1) + (f2 + f3));
      half4 pa0 = {(_Float16)e0, (_Float16)e1, (_Float16)e2, (_Float16)e3};  // tm0, in-lane
      half4 pa1 = {(_Float16)f0, (_Float16)f1, (_Float16)f2, (_Float16)f3};  // tm1

#pragma unroll
      for (int ct = 0; ct < 4; ++ct) {
        half4 glo = __builtin_shufflevector(gv[ct], gv[ct], 0, 1, 2, 3);
        half4 ghi = __builtin_shufflevector(gv[ct], gv[ct], 4, 5, 6, 7);
        acc[nt][ct] = __builtin_amdgcn_mfma_f32_16x16x16f16(pa0, glo, acc[nt][ct], 0, 0, 0);
        acc[nt][ct] = __builtin_amdgcn_mfma_f32_16x16x16f16(pa1, ghi, acc[nt][ct], 0, 0, 0);
      }
    }
  }

  // partial rowsum: lane holds n=l15 (col of S^T); reduce over q groups
#pragma unroll
  for (int nt = 0; nt < 2; ++nt) {
    float v = rsum[nt];
    v += __shfl_xor(v, 16);
    v += __shfl_xor(v, 32);
    if (lane < 16)
      rsumpart[(size_t)(split * NB + b) * NN + nw + nt * 16 + lane] = v;
  }
  // partial y: PV D-layout row n=q*4+r, col c=ct*16+l15
#pragma unroll
  for (int nt = 0; nt < 2; ++nt)
#pragma unroll
    for (int ct = 0; ct < 4; ++ct)
#pragma unroll
      for (int r = 0; r < 4; ++r)
        ypart[((size_t)(split * NB + b) * NN + nw + nt * 16 + q * 4 + r) * 64 + ct * 16 + l15] =
            __float2bfloat16(acc[nt][ct][r]);
}

// ---------------------------------------------------------------------------
// Combine partials + residual + W-conv (MFMA) + BN stats.
// grid (288, B) x 128 (2 waves x 16 n-rows).
// ---------------------------------------------------------------------------
__global__ __launch_bounds__(128) void combine_k(
    const __hip_bfloat16* __restrict__ ypart, const float* __restrict__ rsumpart,
    const float* __restrict__ x, const float* __restrict__ Ww, const float* __restrict__ Wb,
    float* __restrict__ z2, float* __restrict__ psum) {
  __shared__ float rs[2][64];
  int t = threadIdx.x, wv = t >> 6, lane = t & 63;
  int l15 = lane & 15, q = lane >> 4;
  int b = blockIdx.y, n0 = blockIdx.x * 32, nw = n0 + wv * 16;
  int nrow = nw + l15;

  float y0[8], y1[8];
#pragma unroll
  for (int j = 0; j < 8; ++j) { y0[j] = 0.f; y1[j] = 0.f; }
  float rsum = 0.f;
#pragma unroll
  for (int s = 0; s < MSPLIT; ++s) {
    const __hip_bfloat16* yp = ypart + ((size_t)(s * NB + b) * NN + nrow) * 64;
    short8 a = *(const short8*)(yp + q * 8);
    short8 c = *(const short8*)(yp + 32 + q * 8);
#pragma unroll
    for (int j = 0; j < 8; ++j) { y0[j] += b2f(a[j]); y1[j] += b2f(c[j]); }
    rsum += rsumpart[(size_t)(s * NB + b) * NN + nrow];
  }
  float rinv = 1.0f / rsum;

  float z1a[8], z1b[8];
#pragma unroll
  for (int j = 0; j < 8; ++j) {
    z1a[j] = y0[j] * rinv + x[((size_t)b * 64 + q * 8 + j) * NN + nrow];
    z1b[j] = y1[j] * rinv + x[((size_t)b * 64 + 32 + q * 8 + j) * NN + nrow];
  }
  short8 za0 = pack8(z1a), za1 = pack8(z1b);  // A[n-row=l15][k=c]

  short8 wbf[2][2];
#pragma unroll
  for (int ot = 0; ot < 2; ++ot)
#pragma unroll
    for (int kf = 0; kf < 2; ++kf)
      wbf[ot][kf] = ldw8(Ww + (size_t)(ot * 16 + l15) * 64 + kf * 32 + q * 8);

  f32x4 dd[2];
#pragma unroll
  for (int ot = 0; ot < 2; ++ot) {
    float bias = Wb[ot * 16 + l15];
    f32x4 d = (f32x4){bias, bias, bias, bias};
    d = __builtin_amdgcn_mfma_f32_16x16x32_bf16(za0, wbf[ot][0], d, 0, 0, 0);
    d = __builtin_amdgcn_mfma_f32_16x16x32_bf16(za1, wbf[ot][1], d, 0, 0, 0);
#pragma unroll
    for (int r = 0; r < 4; ++r)
      z2[((size_t)b * NN + nw + q * 4 + r) * 32 + ot * 16 + l15] = d[r];
    dd[ot] = d;
  }

#pragma unroll
  for (int ot = 0; ot < 2; ++ot) {
    float ps = (dd[ot][0] + dd[ot][1]) + (dd[ot][2] + dd[ot][3]);
    float ps2 = dd[ot][0] * dd[ot][0] + dd[ot][1] * dd[ot][1] +
                dd[ot][2] * dd[ot][2] + dd[ot][3] * dd[ot][3];
    ps += __shfl_xor(ps, 16);  ps += __shfl_xor(ps, 32);
    ps2 += __shfl_xor(ps2, 16); ps2 += __shfl_xor(ps2, 32);
    if (lane < 16) {
      rs[wv][ot * 16 + lane] = ps;
      rs[wv][32 + ot * 16 + lane] = ps2;
    }
  }
  __syncthreads();
  if (t < 64) atomicAdd(&psum[t], rs[0][t] + rs[1][t]);
}

// ---------------------------------------------------------------------------
// BN finalize + apply + transpose [n][32] -> [32][n].
// ---------------------------------------------------------------------------
__global__ __launch_bounds__(256) void bn_apply(
    const float* __restrict__ z2, const float* __restrict__ psum,
    const float* __restrict__ gamma, const float* __restrict__ beta,
    float* __restrict__ out) {
  __shared__ float ssl[64];
  __shared__ float zt[32][65];
  int t = threadIdx.x, b = blockIdx.y, n0 = blockIdx.x * 64;
  if (t < 32) {
    const float inv = 1.0f / (float)(NB * NN);
    float mean = psum[t] * inv;
    float var = psum[32 + t] * inv - mean * mean;
    float sc = gamma[t] * rsqrtf(var + 1e-5f);
    ssl[t] = sc;
    ssl[32 + t] = beta[t] - mean * sc;
  }
#pragma unroll
  for (int it = 0; it < 2; ++it) {
    int idx = it * 256 + t, r = idx >> 3, seg = idx & 7;
    float4 vv = *(const float4*)(z2 + ((size_t)b * NN + n0 + r) * 32 + seg * 4);
    zt[seg * 4 + 0][r] = vv.x; zt[seg * 4 + 1][r] = vv.y;
    zt[seg * 4 + 2][r] = vv.z; zt[seg * 4 + 3][r] = vv.w;
  }
  __syncthreads();
  int o = t >> 3, nseg = t & 7;
  float sc = ssl[o], sh = ssl[32 + o];
  float4 a, c;
  a.x = zt[o][nseg * 8 + 0] * sc + sh; a.y = zt[o][nseg * 8 + 1] * sc + sh;
  a.z = zt[o][nseg * 8 + 2] * sc + sh; a.w = zt[o][nseg * 8 + 3] * sc + sh;
  c.x = zt[o][nseg * 8 + 4] * sc + sh; c.y = zt[o][nseg * 8 + 5] * sc + sh;
  c.z = zt[o][nseg * 8 + 6] * sc + sh; c.w = zt[o][nseg * 8 + 7] * sc + sh;
  float* po = out + ((size_t)b * 32 + o) * NN + n0 + nseg * 8;
  *(float4*)po = a;
  *(float4*)(po + 4) = c;
}

// ---------------------------------------------------------------------------
extern "C" void kernel_launch(void* const* d_in, const int* in_sizes, int n_in,
                              void* d_out, int out_size, void* d_ws, size_t ws_size,
                              hipStream_t stream) {
  const float* x       = (const float*)d_in[0];
  const float* feature = (const float*)d_in[1];
  const float* g_w     = (const float*)d_in[2];
  const float* g_b     = (const float*)d_in[3];
  const float* theta_w = (const float*)d_in[4];
  const float* theta_b = (const float*)d_in[5];
  const float* phi_w   = (const float*)d_in[6];
  const float* phi_b   = (const float*)d_in[7];
  const float* W_w     = (const float*)d_in[8];
  const float* W_b     = (const float*)d_in[9];
  const float* bn_g    = (const float*)d_in[10];
  const float* bn_b    = (const float*)d_in[11];

  char* ws = (char*)d_ws;
  __hip_bfloat16* Theta    = (__hip_bfloat16*)(ws);             // 4,718,592
  _Float16*       Gcm      = (_Float16*)(ws + 4718592);         // 1,179,648
  __hip_bfloat16* PhiT     = (__hip_bfloat16*)(ws + 5898240);   // 1,179,648
  float*          z2       = (float*)(ws + 7077888);            // 4,718,592
  __hip_bfloat16* ypart    = (__hip_bfloat16*)(ws + 11796480);  // 9,437,184 (MSPLIT=2)
  float*          rsumpart = (float*)(ws + 21233664);           // 294,912
  float*          psum     = (float*)(ws + 21528576);           // 256

  conv_pool_k<<<dim3(288, NB), dim3(256), 0, stream>>>(
      x, feature, theta_w, theta_b, g_w, g_b, phi_w, phi_b, Theta, Gcm, PhiT, psum);
  attn_part<<<dim3(144 * MSPLIT, NB), dim3(128), 0, stream>>>(
      Theta, PhiT, Gcm, ypart, rsumpart);
  combine_k<<<dim3(288, NB), dim3(128), 0, stream>>>(
      ypart, rsumpart, x, W_w, W_b, z2, psum);
  bn_apply<<<dim3(144, NB), dim3(256), 0, stream>>>(
      z2, psum, bn_g, bn_b, (float*)d_out);
}

// Round 7
// 157.913 us; speedup vs baseline: 1.0997x; 1.0997x over previous
//
#include <hip/hip_runtime.h>
#include <hip/hip_bf16.h>

typedef __attribute__((ext_vector_type(8))) short short8;
typedef __attribute__((ext_vector_type(4))) float f32x4;
typedef __attribute__((ext_vector_type(4))) _Float16 half4;
typedef __attribute__((ext_vector_type(8))) _Float16 half8;

#define NB 4
#define NN 9216
#define NM 2304

__device__ inline unsigned pk2(float a, float b) {
  __hip_bfloat16 ha = __float2bfloat16(a), hb = __float2bfloat16(b);
  return (unsigned)*(unsigned short*)&ha | ((unsigned)*(unsigned short*)&hb << 16);
}
__device__ inline short8 pack8(const float* v) {
  short8 s;
#pragma unroll
  for (int j = 0; j < 8; ++j) { __hip_bfloat16 h = __float2bfloat16(v[j]); s[j] = *(short*)&h; }
  return s;
}
__device__ inline short8 ldw8(const float* p) {
  float tmp[8];
  *(float4*)&tmp[0] = *(const float4*)p;
  *(float4*)&tmp[4] = *(const float4*)(p + 4);
  return pack8(tmp);
}

// ---------------------------------------------------------------------------
// Fused conv1x1 (theta,g,phi) + 2x2 maxpool for g/phi.  (r5/r6-verified)
// grid (288, B) x 256; wave owns one 16-wide ot slice.  Gcm f16.
// ---------------------------------------------------------------------------
__global__ __launch_bounds__(256) void conv_pool_k(
    const float* __restrict__ x, const float* __restrict__ feat,
    const float* __restrict__ tw, const float* __restrict__ tbi,
    const float* __restrict__ gw, const float* __restrict__ gbi,
    const float* __restrict__ pw, const float* __restrict__ pbi,
    __hip_bfloat16* __restrict__ Theta, _Float16* __restrict__ Gcm,
    __hip_bfloat16* __restrict__ PhiT, float* __restrict__ psum) {
  int t = threadIdx.x, wv = t >> 6, lane = t & 63, l15 = lane & 15, q = lane >> 4;
  int b = blockIdx.y, bx = blockIdx.x;
  if (bx == 0 && b == 0 && t < 64) psum[t] = 0.f;
  int jt = bx % 6, rp = bx / 6;
  int i0 = rp * 2, j0 = jt * 16;
  int ntop = i0 * 96 + j0;
  int ot = wv;

  short8 wt[2], wg[2], wp1;
#pragma unroll
  for (int kf = 0; kf < 2; ++kf) {
    wt[kf] = ldw8(tw + (size_t)(ot * 16 + l15) * 64 + kf * 32 + q * 8);
    wg[kf] = ldw8(gw + (size_t)(ot * 16 + l15) * 64 + kf * 32 + q * 8);
  }
  wp1 = ldw8(pw + (size_t)(ot * 16 + l15) * 32 + q * 8);

  short8 bxf[2][2], bff[2];
  {
    float tmp[8];
#pragma unroll
    for (int row = 0; row < 2; ++row) {
#pragma unroll
      for (int kf = 0; kf < 2; ++kf) {
#pragma unroll
        for (int j = 0; j < 8; ++j)
          tmp[j] = x[((size_t)b * 64 + kf * 32 + q * 8 + j) * NN + ntop + row * 96 + l15];
        bxf[row][kf] = pack8(tmp);
      }
#pragma unroll
      for (int j = 0; j < 8; ++j)
        tmp[j] = feat[((size_t)b * 32 + q * 8 + j) * NN + ntop + row * 96 + l15];
      bff[row] = pack8(tmp);
    }
  }

  int m = rp * 48 + ((j0 + l15) >> 1);
  bool em = (l15 & 1) == 0;

#pragma unroll
  for (int row = 0; row < 2; ++row) {
    f32x4 d;
#pragma unroll
    for (int r = 0; r < 4; ++r) d[r] = tbi[ot * 16 + q * 4 + r];
    d = __builtin_amdgcn_mfma_f32_16x16x32_bf16(wt[0], bxf[row][0], d, 0, 0, 0);
    d = __builtin_amdgcn_mfma_f32_16x16x32_bf16(wt[1], bxf[row][1], d, 0, 0, 0);
    size_t base = ((size_t)b * NN + ntop + row * 96 + l15) * 64 + ot * 16 + q * 4;
    *(unsigned*)(Theta + base) = pk2(d[0], d[1]);
    *(unsigned*)(Theta + base + 2) = pk2(d[2], d[3]);
  }
  {
    f32x4 d0, d1;
#pragma unroll
    for (int r = 0; r < 4; ++r) { float bb = gbi[ot * 16 + q * 4 + r]; d0[r] = bb; d1[r] = bb; }
    d0 = __builtin_amdgcn_mfma_f32_16x16x32_bf16(wg[0], bxf[0][0], d0, 0, 0, 0);
    d0 = __builtin_amdgcn_mfma_f32_16x16x32_bf16(wg[1], bxf[0][1], d0, 0, 0, 0);
    d1 = __builtin_amdgcn_mfma_f32_16x16x32_bf16(wg[0], bxf[1][0], d1, 0, 0, 0);
    d1 = __builtin_amdgcn_mfma_f32_16x16x32_bf16(wg[1], bxf[1][1], d1, 0, 0, 0);
    float h[4];
#pragma unroll
    for (int r = 0; r < 4; ++r) {
      float v = fmaxf(d0[r], d1[r]);
      h[r] = fmaxf(v, __shfl_xor(v, 1));
    }
    if (em) {
#pragma unroll
      for (int r = 0; r < 4; ++r)
        Gcm[((size_t)b * 64 + ot * 16 + q * 4 + r) * NM + m] = (_Float16)h[r];
    }
  }
  {
    f32x4 d0, d1;
#pragma unroll
    for (int r = 0; r < 4; ++r) { float bb = pbi[ot * 16 + q * 4 + r]; d0[r] = bb; d1[r] = bb; }
    d0 = __builtin_amdgcn_mfma_f32_16x16x32_bf16(wp1, bff[0], d0, 0, 0, 0);
    d1 = __builtin_amdgcn_mfma_f32_16x16x32_bf16(wp1, bff[1], d1, 0, 0, 0);
    float h[4];
#pragma unroll
    for (int r = 0; r < 4; ++r) {
      float v = fmaxf(d0[r], d1[r]);
      h[r] = fmaxf(v, __shfl_xor(v, 1));
    }
    if (em) {
      size_t base = ((size_t)b * NM + m) * 64 + ot * 16 + q * 4;
      *(unsigned*)(PhiT + base) = pk2(h[0], h[1]);
      *(unsigned*)(PhiT + base + 2) = pk2(h[2], h[3]);
    }
  }
}

// ---------------------------------------------------------------------------
// Fully-fused attention: full-M sweep + residual + W-conv + BN stats.
// grid (144, B) x 256 (4 waves x 16 n-rows).  36 chunks of 64 m.
// S^T = Phi·Theta^T (bf16 K=32, r6-verified); PV in-register via f16 K=16
// (r6-verified); epilogue = r4-verified zacc transpose + W-conv + BN atomics.
// ---------------------------------------------------------------------------
__global__ __launch_bounds__(256) void attn_k(
    const __hip_bfloat16* __restrict__ Theta, const __hip_bfloat16* __restrict__ PhiT,
    const _Float16* __restrict__ Gcm, const float* __restrict__ x,
    const float* __restrict__ Ww, const float* __restrict__ Wb,
    float* __restrict__ z2, float* __restrict__ psum) {
  __shared__ union {
    struct {
      __hip_bfloat16 phis[64][72];  // [m][c]           9216 B
      _Float16 gs2[64][72];         // [c][m-interleav]  9216 B
    } s;
    __hip_bfloat16 zacc[64][72];    // z1 [n][c], epilogue
  } u;
  __shared__ float rs[4][64];

  int t = threadIdx.x, wv = t >> 6, lane = t & 63;
  int l15 = lane & 15, q = lane >> 4;
  int b = blockIdx.y;
  int n0 = blockIdx.x * 64, nw = n0 + wv * 16;

  // Theta B-frags (held): B[k=c=kf*32+q*8+j][n=l15]
  short8 tb[2];
#pragma unroll
  for (int kf = 0; kf < 2; ++kf)
    tb[kf] = *(const short8*)(Theta + ((size_t)b * NN + nw + l15) * 64 + kf * 32 + q * 8);

  f32x4 acc[4];
#pragma unroll
  for (int ct = 0; ct < 4; ++ct) acc[ct] = (f32x4){0.f, 0.f, 0.f, 0.f};
  float rsum = 0.f;

  const __hip_bfloat16* phibase = PhiT + (size_t)b * NM * 64;
  const _Float16* gbase = Gcm + (size_t)b * 64 * NM;

  for (int ck = 0; ck < NM / 64; ++ck) {   // 36 chunks of 64 m
    int m0 = ck * 64;
    __syncthreads();
#pragma unroll
    for (int p = 0; p < 2; ++p) {  // stage Phi: 64 m x 64 c
      int idx = p * 256 + t, r = idx >> 3, seg = idx & 7;
      *(uint4*)&u.s.phis[r][seg * 8] = *(const uint4*)(phibase + (size_t)(m0 + r) * 64 + seg * 8);
    }
#pragma unroll
    for (int p = 0; p < 2; ++p) {  // stage G interleaved: pair pp, quad qq
      int idx = p * 256 + t, c = idx >> 3, g = idx & 7;
      int pp = g >> 2, qq = g & 3;
      const _Float16* gc = gbase + (size_t)c * NM + m0 + pp * 32 + qq * 4;
      uint2 lo = *(const uint2*)gc;
      uint2 hi = *(const uint2*)(gc + 16);
      uint4 w; w.x = lo.x; w.y = lo.y; w.z = hi.x; w.w = hi.y;
      *(uint4*)&u.s.gs2[c][g * 8] = w;
    }
    __syncthreads();

    // Phi A-frags: A[m=tm*16+l15][k=c=kf*32+q*8+j]
    short8 pha[4][2];
#pragma unroll
    for (int tm = 0; tm < 4; ++tm)
#pragma unroll
      for (int kf = 0; kf < 2; ++kf)
        pha[tm][kf] = *(const short8*)&u.s.phis[tm * 16 + l15][kf * 32 + q * 8];
    // G B-frags: gv[ct][pp] elements 0..3 = tm=2pp (k=q*4+j), 4..7 = tm=2pp+1
    half8 gv[4][2];
#pragma unroll
    for (int ct = 0; ct < 4; ++ct)
#pragma unroll
      for (int pp = 0; pp < 2; ++pp)
        gv[ct][pp] = *(const half8*)&u.s.gs2[ct * 16 + l15][pp * 32 + q * 8];

    half4 pa[4];
#pragma unroll
    for (int tm = 0; tm < 4; ++tm) {
      f32x4 s = (f32x4){0.f, 0.f, 0.f, 0.f};
      s = __builtin_amdgcn_mfma_f32_16x16x32_bf16(pha[tm][0], tb[0], s, 0, 0, 0);
      s = __builtin_amdgcn_mfma_f32_16x16x32_bf16(pha[tm][1], tb[1], s, 0, 0, 0);
      float e0 = __expf(s[0]), e1 = __expf(s[1]), e2 = __expf(s[2]), e3 = __expf(s[3]);
      rsum += (e0 + e1) + (e2 + e3);
      pa[tm] = (half4){(_Float16)e0, (_Float16)e1, (_Float16)e2, (_Float16)e3};
    }
#pragma unroll
    for (int ct = 0; ct < 4; ++ct)
#pragma unroll
      for (int pp = 0; pp < 2; ++pp) {
        half4 glo = __builtin_shufflevector(gv[ct][pp], gv[ct][pp], 0, 1, 2, 3);
        half4 ghi = __builtin_shufflevector(gv[ct][pp], gv[ct][pp], 4, 5, 6, 7);
        acc[ct] = __builtin_amdgcn_mfma_f32_16x16x16f16(pa[2 * pp], glo, acc[ct], 0, 0, 0);
        acc[ct] = __builtin_amdgcn_mfma_f32_16x16x16f16(pa[2 * pp + 1], ghi, acc[ct], 0, 0, 0);
      }
  }

  // rowsum for col n=l15: reduce over the 4 q-groups
  float v = rsum;
  v += __shfl_xor(v, 16);
  v += __shfl_xor(v, 32);
  float rinv = 1.0f / v;
  float riv[4];
#pragma unroll
  for (int r = 0; r < 4; ++r) riv[r] = __shfl(rinv, q * 4 + r);

  __syncthreads();  // all waves done with staging LDS (zacc aliases it)

  // z1 = y*rinv + x -> zacc[n][c] bf16  (D: row n=q*4+r, col c=ct*16+l15)
#pragma unroll
  for (int ct = 0; ct < 4; ++ct) {
#pragma unroll
    for (int r = 0; r < 4; ++r) {
      float xv = x[((size_t)b * 64 + ct * 16 + l15) * NN + nw + q * 4 + r];
      u.zacc[wv * 16 + q * 4 + r][ct * 16 + l15] =
          __float2bfloat16(acc[ct][r] * riv[r] + xv);
    }
  }
  __syncthreads();

  // W-conv: A = zacc rows (A[n=l15][k=c]), B = Ww
  short8 wbf[2][2];
#pragma unroll
  for (int ot = 0; ot < 2; ++ot)
#pragma unroll
    for (int kf = 0; kf < 2; ++kf)
      wbf[ot][kf] = ldw8(Ww + (size_t)(ot * 16 + l15) * 64 + kf * 32 + q * 8);
  short8 za0 = *(const short8*)&u.zacc[wv * 16 + l15][q * 8];
  short8 za1 = *(const short8*)&u.zacc[wv * 16 + l15][32 + q * 8];

  f32x4 dd[2];
#pragma unroll
  for (int ot = 0; ot < 2; ++ot) {
    float bias = Wb[ot * 16 + l15];
    f32x4 d = (f32x4){bias, bias, bias, bias};
    d = __builtin_amdgcn_mfma_f32_16x16x32_bf16(za0, wbf[ot][0], d, 0, 0, 0);
    d = __builtin_amdgcn_mfma_f32_16x16x32_bf16(za1, wbf[ot][1], d, 0, 0, 0);
#pragma unroll
    for (int r = 0; r < 4; ++r)
      z2[((size_t)b * NN + nw + q * 4 + r) * 32 + ot * 16 + l15] = d[r];
    dd[ot] = d;
  }

  // BN stats: block partials -> 64 global atomics
#pragma unroll
  for (int ot = 0; ot < 2; ++ot) {
    float ps = (dd[ot][0] + dd[ot][1]) + (dd[ot][2] + dd[ot][3]);
    float ps2 = dd[ot][0] * dd[ot][0] + dd[ot][1] * dd[ot][1] +
                dd[ot][2] * dd[ot][2] + dd[ot][3] * dd[ot][3];
    ps += __shfl_xor(ps, 16);  ps += __shfl_xor(ps, 32);
    ps2 += __shfl_xor(ps2, 16); ps2 += __shfl_xor(ps2, 32);
    if (lane < 16) {
      rs[wv][ot * 16 + lane] = ps;
      rs[wv][32 + ot * 16 + lane] = ps2;
    }
  }
  __syncthreads();
  if (t < 64) {
    float tot = rs[0][t] + rs[1][t] + rs[2][t] + rs[3][t];
    atomicAdd(&psum[t], tot);
  }
}

// ---------------------------------------------------------------------------
// BN finalize + apply + transpose [n][32] -> [32][n].
// ---------------------------------------------------------------------------
__global__ __launch_bounds__(256) void bn_apply(
    const float* __restrict__ z2, const float* __restrict__ psum,
    const float* __restrict__ gamma, const float* __restrict__ beta,
    float* __restrict__ out) {
  __shared__ float ssl[64];
  __shared__ float zt[32][65];
  int t = threadIdx.x, b = blockIdx.y, n0 = blockIdx.x * 64;
  if (t < 32) {
    const float inv = 1.0f / (float)(NB * NN);
    float mean = psum[t] * inv;
    float var = psum[32 + t] * inv - mean * mean;
    float sc = gamma[t] * rsqrtf(var + 1e-5f);
    ssl[t] = sc;
    ssl[32 + t] = beta[t] - mean * sc;
  }
#pragma unroll
  for (int it = 0; it < 2; ++it) {
    int idx = it * 256 + t, r = idx >> 3, seg = idx & 7;
    float4 vv = *(const float4*)(z2 + ((size_t)b * NN + n0 + r) * 32 + seg * 4);
    zt[seg * 4 + 0][r] = vv.x; zt[seg * 4 + 1][r] = vv.y;
    zt[seg * 4 + 2][r] = vv.z; zt[seg * 4 + 3][r] = vv.w;
  }
  __syncthreads();
  int o = t >> 3, nseg = t & 7;
  float sc = ssl[o], sh = ssl[32 + o];
  float4 a, c;
  a.x = zt[o][nseg * 8 + 0] * sc + sh; a.y = zt[o][nseg * 8 + 1] * sc + sh;
  a.z = zt[o][nseg * 8 + 2] * sc + sh; a.w = zt[o][nseg * 8 + 3] * sc + sh;
  c.x = zt[o][nseg * 8 + 4] * sc + sh; c.y = zt[o][nseg * 8 + 5] * sc + sh;
  c.z = zt[o][nseg * 8 + 6] * sc + sh; c.w = zt[o][nseg * 8 + 7] * sc + sh;
  float* po = out + ((size_t)b * 32 + o) * NN + n0 + nseg * 8;
  *(float4*)po = a;
  *(float4*)(po + 4) = c;
}

// ---------------------------------------------------------------------------
extern "C" void kernel_launch(void* const* d_in, const int* in_sizes, int n_in,
                              void* d_out, int out_size, void* d_ws, size_t ws_size,
                              hipStream_t stream) {
  const float* x       = (const float*)d_in[0];
  const float* feature = (const float*)d_in[1];
  const float* g_w     = (const float*)d_in[2];
  const float* g_b     = (const float*)d_in[3];
  const float* theta_w = (const float*)d_in[4];
  const float* theta_b = (const float*)d_in[5];
  const float* phi_w   = (const float*)d_in[6];
  const float* phi_b   = (const float*)d_in[7];
  const float* W_w     = (const float*)d_in[8];
  const float* W_b     = (const float*)d_in[9];
  const float* bn_g    = (const float*)d_in[10];
  const float* bn_b    = (const float*)d_in[11];

  char* ws = (char*)d_ws;
  __hip_bfloat16* Theta = (__hip_bfloat16*)(ws);             // 4,718,592
  _Float16*       Gcm   = (_Float16*)(ws + 4718592);         // 1,179,648
  __hip_bfloat16* PhiT  = (__hip_bfloat16*)(ws + 5898240);   // 1,179,648
  float*          z2    = (float*)(ws + 7077888);            // 4,718,592
  float*          psum  = (float*)(ws + 11796480);           // 256

  conv_pool_k<<<dim3(288, NB), dim3(256), 0, stream>>>(
      x, feature, theta_w, theta_b, g_w, g_b, phi_w, phi_b, Theta, Gcm, PhiT, psum);
  attn_k<<<dim3(144, NB), dim3(256), 0, stream>>>(
      Theta, PhiT, Gcm, x, W_w, W_b, z2, psum);
  bn_apply<<<dim3(144, NB), dim3(256), 0, stream>>>(
      z2, psum, bn_g, bn_b, (float*)d_out);
}

// Round 8
// 148.795 us; speedup vs baseline: 1.1671x; 1.0613x over previous
//
#include <hip/hip_runtime.h>
#include <hip/hip_bf16.h>

typedef __attribute__((ext_vector_type(8))) short short8;
typedef __attribute__((ext_vector_type(4))) float f32x4;
typedef __attribute__((ext_vector_type(4))) _Float16 half4;

#define NB 4
#define NN 9216
#define NM 2304

__device__ inline unsigned pk2(float a, float b) {
  __hip_bfloat16 ha = __float2bfloat16(a), hb = __float2bfloat16(b);
  return (unsigned)*(unsigned short*)&ha | ((unsigned)*(unsigned short*)&hb << 16);
}
__device__ inline float ubf(unsigned u) {  // low 16 bits = bf16
  unsigned v = u << 16; return *(float*)&v;
}
__device__ inline short8 pack8(const float* v) {
  short8 s;
#pragma unroll
  for (int j = 0; j < 8; ++j) { __hip_bfloat16 h = __float2bfloat16(v[j]); s[j] = *(short*)&h; }
  return s;
}
__device__ inline short8 ldw8(const float* p) {
  float tmp[8];
  *(float4*)&tmp[0] = *(const float4*)p;
  *(float4*)&tmp[4] = *(const float4*)(p + 4);
  return pack8(tmp);
}

// ---------------------------------------------------------------------------
// Fused conv1x1 (theta,g,phi) + 2x2 maxpool for g/phi.
// LDS-transposed staging: x/feat read ONCE per block (coalesced float4),
// frags built as b128 LDS reads.  grid (144, B) x 256; wave = ot slice;
// block covers 1 row-pair x 32 cols (64 n).
// ---------------------------------------------------------------------------
__global__ __launch_bounds__(256, 3) void conv_pool_k(
    const float* __restrict__ x, const float* __restrict__ feat,
    const float* __restrict__ tw, const float* __restrict__ tbi,
    const float* __restrict__ gw, const float* __restrict__ gbi,
    const float* __restrict__ pw, const float* __restrict__ pbi,
    __hip_bfloat16* __restrict__ Theta, _Float16* __restrict__ Gcm,
    __hip_bfloat16* __restrict__ PhiT, float* __restrict__ psum) {
  __shared__ float xs[64][68];   // [nloc][c]  (68*4 B = 16B-aligned rows)
  __shared__ float fs[64][36];   // [nloc][c]
  int t = threadIdx.x, wv = t >> 6, lane = t & 63, l15 = lane & 15, q = lane >> 4;
  int b = blockIdx.y, bx = blockIdx.x;
  if (bx == 0 && b == 0 && t < 64) psum[t] = 0.f;
  int jt = bx % 3, rp = bx / 3;      // jt 0..2 (32-col tiles), rp 0..47 (row pairs)
  int i0 = rp * 2, j0 = jt * 32;
  int ot = wv;

  // stage x: [c][2x32 n] -> xs[nloc][c], nloc = row*32 + cloc
  {
#pragma unroll
    for (int p = 0; p < 4; ++p) {
      int idx = p * 256 + t;
      int c = idx >> 4, s = idx & 15;
      int row = s >> 3, cl = (s & 7) * 4;
      float4 v = *(const float4*)(x + ((size_t)b * 64 + c) * NN + (i0 + row) * 96 + j0 + cl);
      int nl = row * 32 + cl;
      xs[nl][c] = v.x; xs[nl + 1][c] = v.y; xs[nl + 2][c] = v.z; xs[nl + 3][c] = v.w;
    }
#pragma unroll
    for (int p = 0; p < 2; ++p) {
      int idx = p * 256 + t;
      int c = idx >> 4, s = idx & 15;
      int row = s >> 3, cl = (s & 7) * 4;
      float4 v = *(const float4*)(feat + ((size_t)b * 32 + c) * NN + (i0 + row) * 96 + j0 + cl);
      int nl = row * 32 + cl;
      fs[nl][c] = v.x; fs[nl + 1][c] = v.y; fs[nl + 2][c] = v.z; fs[nl + 3][c] = v.w;
    }
  }

  // weights for this ot: A[o=ot*16+l15][k=c]
  short8 wt[2], wg[2], wp1;
#pragma unroll
  for (int kf = 0; kf < 2; ++kf) {
    wt[kf] = ldw8(tw + (size_t)(ot * 16 + l15) * 64 + kf * 32 + q * 8);
    wg[kf] = ldw8(gw + (size_t)(ot * 16 + l15) * 64 + kf * 32 + q * 8);
  }
  wp1 = ldw8(pw + (size_t)(ot * 16 + l15) * 32 + q * 8);

  __syncthreads();

  // B-frags: B[k=c=kf*32+q*8+j][n=tl*16+l15]; tl: 0=r0c0-15 1=r0c16-31 2=r1c0-15 3=r1c16-31
  short8 bxf[4][2], bff[4];
  {
    float tmp[8];
#pragma unroll
    for (int tl = 0; tl < 4; ++tl) {
#pragma unroll
      for (int kf = 0; kf < 2; ++kf) {
        *(float4*)&tmp[0] = *(float4*)&xs[tl * 16 + l15][kf * 32 + q * 8];
        *(float4*)&tmp[4] = *(float4*)&xs[tl * 16 + l15][kf * 32 + q * 8 + 4];
        bxf[tl][kf] = pack8(tmp);
      }
      *(float4*)&tmp[0] = *(float4*)&fs[tl * 16 + l15][q * 8];
      *(float4*)&tmp[4] = *(float4*)&fs[tl * 16 + l15][q * 8 + 4];
      bff[tl] = pack8(tmp);
    }
  }

  // ---- theta: all 4 tiles ----
#pragma unroll
  for (int tl = 0; tl < 4; ++tl) {
    f32x4 d;
#pragma unroll
    for (int r = 0; r < 4; ++r) d[r] = tbi[ot * 16 + q * 4 + r];
    d = __builtin_amdgcn_mfma_f32_16x16x32_bf16(wt[0], bxf[tl][0], d, 0, 0, 0);
    d = __builtin_amdgcn_mfma_f32_16x16x32_bf16(wt[1], bxf[tl][1], d, 0, 0, 0);
    int n = (i0 + (tl >> 1)) * 96 + j0 + (tl & 1) * 16 + l15;
    size_t base = ((size_t)b * NN + n) * 64 + ot * 16 + q * 4;
    *(unsigned*)(Theta + base) = pk2(d[0], d[1]);
    *(unsigned*)(Theta + base + 2) = pk2(d[2], d[3]);
  }

  int mrow = rp * 48 + jt * 16;
  bool em = (l15 & 1) == 0;
  // ---- g + pool (vertical tiles ch / ch+2, horizontal shfl pair) ----
#pragma unroll
  for (int ch = 0; ch < 2; ++ch) {
    f32x4 d0, d1;
#pragma unroll
    for (int r = 0; r < 4; ++r) { float bb = gbi[ot * 16 + q * 4 + r]; d0[r] = bb; d1[r] = bb; }
    d0 = __builtin_amdgcn_mfma_f32_16x16x32_bf16(wg[0], bxf[ch][0], d0, 0, 0, 0);
    d0 = __builtin_amdgcn_mfma_f32_16x16x32_bf16(wg[1], bxf[ch][1], d0, 0, 0, 0);
    d1 = __builtin_amdgcn_mfma_f32_16x16x32_bf16(wg[0], bxf[ch + 2][0], d1, 0, 0, 0);
    d1 = __builtin_amdgcn_mfma_f32_16x16x32_bf16(wg[1], bxf[ch + 2][1], d1, 0, 0, 0);
    float h[4];
#pragma unroll
    for (int r = 0; r < 4; ++r) {
      float v = fmaxf(d0[r], d1[r]);
      h[r] = fmaxf(v, __shfl_xor(v, 1));
    }
    if (em) {
      int m = mrow + ch * 8 + (l15 >> 1);
#pragma unroll
      for (int r = 0; r < 4; ++r)
        Gcm[((size_t)b * 64 + ot * 16 + q * 4 + r) * NM + m] = (_Float16)h[r];
    }
  }
  // ---- phi + pool ----
#pragma unroll
  for (int ch = 0; ch < 2; ++ch) {
    f32x4 d0, d1;
#pragma unroll
    for (int r = 0; r < 4; ++r) { float bb = pbi[ot * 16 + q * 4 + r]; d0[r] = bb; d1[r] = bb; }
    d0 = __builtin_amdgcn_mfma_f32_16x16x32_bf16(wp1, bff[ch], d0, 0, 0, 0);
    d1 = __builtin_amdgcn_mfma_f32_16x16x32_bf16(wp1, bff[ch + 2], d1, 0, 0, 0);
    float h[4];
#pragma unroll
    for (int r = 0; r < 4; ++r) {
      float v = fmaxf(d0[r], d1[r]);
      h[r] = fmaxf(v, __shfl_xor(v, 1));
    }
    if (em) {
      int m = mrow + ch * 8 + (l15 >> 1);
      size_t base = ((size_t)b * NM + m) * 64 + ot * 16 + q * 4;
      *(unsigned*)(PhiT + base) = pk2(h[0], h[1]);
      *(unsigned*)(PhiT + base + 2) = pk2(h[2], h[3]);
    }
  }
}

// ---------------------------------------------------------------------------
// Fully-fused attention, waves split over m (no duplicated frag reads).
// grid (144, B) x 256.  Chunk = 64 m; wave owns a 16-m quarter, all 64 n.
// S^T = Phi·Theta^T (bf16 K=32); PV in-register f16 K=16 (partial over m);
// epilogue: cross-wave zpart reduce (r3) + rowsum scale + residual +
// W-conv MFMA + BN atomics (r7).
// ---------------------------------------------------------------------------
__global__ __launch_bounds__(256, 3) void attn_k(
    const __hip_bfloat16* __restrict__ Theta, const __hip_bfloat16* __restrict__ PhiT,
    const _Float16* __restrict__ Gcm, const float* __restrict__ x,
    const float* __restrict__ Ww, const float* __restrict__ Wb,
    float* __restrict__ z2, float* __restrict__ psum) {
  __shared__ union {
    struct { __hip_bfloat16 phis[64][72]; _Float16 gs[64][72]; } st;      // 18432 B
    struct { __hip_bfloat16 zpart[4][64][68]; __hip_bfloat16 zacc[64][72]; } ep; // 44032 B
  } u;
  __shared__ float rs[4][64];

  int t = threadIdx.x, wv = t >> 6, lane = t & 63;
  int l15 = lane & 15, q = lane >> 4;
  int b = blockIdx.y;
  int n0 = blockIdx.x * 64;

  // Theta B-frags for all 4 n-tiles (held): B[k=c=kf*32+q*8+j][n=l15]
  short8 tb[4][2];
#pragma unroll
  for (int nt = 0; nt < 4; ++nt)
#pragma unroll
    for (int kf = 0; kf < 2; ++kf)
      tb[nt][kf] = *(const short8*)(Theta + ((size_t)b * NN + n0 + nt * 16 + l15) * 64 + kf * 32 + q * 8);

  f32x4 acc[4][4];
#pragma unroll
  for (int nt = 0; nt < 4; ++nt)
#pragma unroll
    for (int ct = 0; ct < 4; ++ct) acc[nt][ct] = (f32x4){0.f, 0.f, 0.f, 0.f};
  float rsum[4] = {0.f, 0.f, 0.f, 0.f};

  const __hip_bfloat16* phibase = PhiT + (size_t)b * NM * 64;
  const _Float16* gbase = Gcm + (size_t)b * 64 * NM;

  for (int ck = 0; ck < NM / 64; ++ck) {   // 36 chunks of 64 m
    int m0 = ck * 64;
    __syncthreads();
#pragma unroll
    for (int p = 0; p < 2; ++p) {  // stage Phi: 64 m x 64 c
      int idx = p * 256 + t, r = idx >> 3, seg = idx & 7;
      *(uint4*)&u.st.phis[r][seg * 8] = *(const uint4*)(phibase + (size_t)(m0 + r) * 64 + seg * 8);
    }
#pragma unroll
    for (int p = 0; p < 2; ++p) {  // stage G plain: 64 c x 64 m (f16)
      int idx = p * 256 + t, c = idx >> 3, seg = idx & 7;
      *(uint4*)&u.st.gs[c][seg * 8] = *(const uint4*)(gbase + (size_t)c * NM + m0 + seg * 8);
    }
    __syncthreads();

    // own m-quarter frags: A[m=wv*16+l15][k=c]; G B[k=m=wv*16+q*4+j][c=l15]
    short8 pha[2];
#pragma unroll
    for (int kf = 0; kf < 2; ++kf)
      pha[kf] = *(const short8*)&u.st.phis[wv * 16 + l15][kf * 32 + q * 8];
    half4 gv[4];
#pragma unroll
    for (int ct = 0; ct < 4; ++ct)
      gv[ct] = *(const half4*)&u.st.gs[ct * 16 + l15][wv * 16 + q * 4];

    half4 pa[4];
#pragma unroll
    for (int nt = 0; nt < 4; ++nt) {
      // S^T quarter: D row m = wv*16+q*4+r, col n = nt*16+l15
      f32x4 s = (f32x4){0.f, 0.f, 0.f, 0.f};
      s = __builtin_amdgcn_mfma_f32_16x16x32_bf16(pha[0], tb[nt][0], s, 0, 0, 0);
      s = __builtin_amdgcn_mfma_f32_16x16x32_bf16(pha[1], tb[nt][1], s, 0, 0, 0);
      float e0 = __expf(s[0]), e1 = __expf(s[1]), e2 = __expf(s[2]), e3 = __expf(s[3]);
      rsum[nt] += (e0 + e1) + (e2 + e3);
      pa[nt] = (half4){(_Float16)e0, (_Float16)e1, (_Float16)e2, (_Float16)e3};
    }
#pragma unroll
    for (int nt = 0; nt < 4; ++nt)
#pragma unroll
      for (int ct = 0; ct < 4; ++ct)
        acc[nt][ct] = __builtin_amdgcn_mfma_f32_16x16x16f16(pa[nt], gv[ct], acc[nt][ct], 0, 0, 0);
  }

  // partial rowsums (this wave's 16-m slice) -> rs[wv][n]
#pragma unroll
  for (int nt = 0; nt < 4; ++nt) {
    float v = rsum[nt];
    v += __shfl_xor(v, 16);
    v += __shfl_xor(v, 32);
    if (lane < 16) rs[wv][nt * 16 + lane] = v;
  }
  __syncthreads();   // all waves done reading staging LDS (zpart aliases it)

  // partial y -> zpart[wv][n][c]  (D: row n = q*4+r within nt, col c = ct*16+l15)
#pragma unroll
  for (int nt = 0; nt < 4; ++nt)
#pragma unroll
    for (int ct = 0; ct < 4; ++ct)
#pragma unroll
      for (int r = 0; r < 4; ++r)
        u.ep.zpart[wv][nt * 16 + q * 4 + r][ct * 16 + l15] = __float2bfloat16(acc[nt][ct][r]);
  __syncthreads();

  // combine: wave wv owns rows wv*16..+15; lane covers c = q*16..+15
  {
    int row = wv * 16 + l15;
    float tot = rs[0][row] + rs[1][row] + rs[2][row] + rs[3][row];
    float rinv = 1.0f / tot;
    float ys[16];
#pragma unroll
    for (int j4 = 0; j4 < 4; ++j4) {
      uint2 p0 = *(const uint2*)&u.ep.zpart[0][row][q * 16 + j4 * 4];
      ys[j4 * 4 + 0] = ubf(p0.x & 0xffffu); ys[j4 * 4 + 1] = ubf(p0.x >> 16);
      ys[j4 * 4 + 2] = ubf(p0.y & 0xffffu); ys[j4 * 4 + 3] = ubf(p0.y >> 16);
    }
#pragma unroll
    for (int wvv = 1; wvv < 4; ++wvv) {
#pragma unroll
      for (int j4 = 0; j4 < 4; ++j4) {
        uint2 p0 = *(const uint2*)&u.ep.zpart[wvv][row][q * 16 + j4 * 4];
        ys[j4 * 4 + 0] += ubf(p0.x & 0xffffu); ys[j4 * 4 + 1] += ubf(p0.x >> 16);
        ys[j4 * 4 + 2] += ubf(p0.y & 0xffffu); ys[j4 * 4 + 3] += ubf(p0.y >> 16);
      }
    }
    float z1[16];
#pragma unroll
    for (int i = 0; i < 16; ++i)
      z1[i] = ys[i] * rinv + x[((size_t)b * 64 + q * 16 + i) * NN + n0 + row];
#pragma unroll
    for (int i2 = 0; i2 < 8; ++i2)
      *(unsigned*)&u.ep.zacc[row][q * 16 + 2 * i2] = pk2(z1[2 * i2], z1[2 * i2 + 1]);
  }
  __syncthreads();

  // W-conv: A = zacc rows (A[n=l15][k=c]), B = Ww; rows nw = n0+wv*16
  int nw = n0 + wv * 16;
  short8 wbf[2][2];
#pragma unroll
  for (int ot = 0; ot < 2; ++ot)
#pragma unroll
    for (int kf = 0; kf < 2; ++kf)
      wbf[ot][kf] = ldw8(Ww + (size_t)(ot * 16 + l15) * 64 + kf * 32 + q * 8);
  short8 za0 = *(const short8*)&u.ep.zacc[wv * 16 + l15][q * 8];
  short8 za1 = *(const short8*)&u.ep.zacc[wv * 16 + l15][32 + q * 8];

  f32x4 dd[2];
#pragma unroll
  for (int ot = 0; ot < 2; ++ot) {
    float bias = Wb[ot * 16 + l15];
    f32x4 d = (f32x4){bias, bias, bias, bias};
    d = __builtin_amdgcn_mfma_f32_16x16x32_bf16(za0, wbf[ot][0], d, 0, 0, 0);
    d = __builtin_amdgcn_mfma_f32_16x16x32_bf16(za1, wbf[ot][1], d, 0, 0, 0);
#pragma unroll
    for (int r = 0; r < 4; ++r)
      z2[((size_t)b * NN + nw + q * 4 + r) * 32 + ot * 16 + l15] = d[r];
    dd[ot] = d;
  }

  // BN stats: block partials -> 64 global atomics (rs reused after barrier)
  __syncthreads();
#pragma unroll
  for (int ot = 0; ot < 2; ++ot) {
    float ps = (dd[ot][0] + dd[ot][1]) + (dd[ot][2] + dd[ot][3]);
    float ps2 = dd[ot][0] * dd[ot][0] + dd[ot][1] * dd[ot][1] +
                dd[ot][2] * dd[ot][2] + dd[ot][3] * dd[ot][3];
    ps += __shfl_xor(ps, 16);  ps += __shfl_xor(ps, 32);
    ps2 += __shfl_xor(ps2, 16); ps2 += __shfl_xor(ps2, 32);
    if (lane < 16) {
      rs[wv][ot * 16 + lane] = ps;
      rs[wv][32 + ot * 16 + lane] = ps2;
    }
  }
  __syncthreads();
  if (t < 64) {
    float tot = rs[0][t] + rs[1][t] + rs[2][t] + rs[3][t];
    atomicAdd(&psum[t], tot);
  }
}

// ---------------------------------------------------------------------------
// BN finalize + apply + transpose [n][32] -> [32][n].
// ---------------------------------------------------------------------------
__global__ __launch_bounds__(256) void bn_apply(
    const float* __restrict__ z2, const float* __restrict__ psum,
    const float* __restrict__ gamma, const float* __restrict__ beta,
    float* __restrict__ out) {
  __shared__ float ssl[64];
  __shared__ float zt[32][65];
  int t = threadIdx.x, b = blockIdx.y, n0 = blockIdx.x * 64;
  if (t < 32) {
    const float inv = 1.0f / (float)(NB * NN);
    float mean = psum[t] * inv;
    float var = psum[32 + t] * inv - mean * mean;
    float sc = gamma[t] * rsqrtf(var + 1e-5f);
    ssl[t] = sc;
    ssl[32 + t] = beta[t] - mean * sc;
  }
#pragma unroll
  for (int it = 0; it < 2; ++it) {
    int idx = it * 256 + t, r = idx >> 3, seg = idx & 7;
    float4 vv = *(const float4*)(z2 + ((size_t)b * NN + n0 + r) * 32 + seg * 4);
    zt[seg * 4 + 0][r] = vv.x; zt[seg * 4 + 1][r] = vv.y;
    zt[seg * 4 + 2][r] = vv.z; zt[seg * 4 + 3][r] = vv.w;
  }
  __syncthreads();
  int o = t >> 3, nseg = t & 7;
  float sc = ssl[o], sh = ssl[32 + o];
  float4 a, c;
  a.x = zt[o][nseg * 8 + 0] * sc + sh; a.y = zt[o][nseg * 8 + 1] * sc + sh;
  a.z = zt[o][nseg * 8 + 2] * sc + sh; a.w = zt[o][nseg * 8 + 3] * sc + sh;
  c.x = zt[o][nseg * 8 + 4] * sc + sh; c.y = zt[o][nseg * 8 + 5] * sc + sh;
  c.z = zt[o][nseg * 8 + 6] * sc + sh; c.w = zt[o][nseg * 8 + 7] * sc + sh;
  float* po = out + ((size_t)b * 32 + o) * NN + n0 + nseg * 8;
  *(float4*)po = a;
  *(float4*)(po + 4) = c;
}

// ---------------------------------------------------------------------------
extern "C" void kernel_launch(void* const* d_in, const int* in_sizes, int n_in,
                              void* d_out, int out_size, void* d_ws, size_t ws_size,
                              hipStream_t stream) {
  const float* x       = (const float*)d_in[0];
  const float* feature = (const float*)d_in[1];
  const float* g_w     = (const float*)d_in[2];
  const float* g_b     = (const float*)d_in[3];
  const float* theta_w = (const float*)d_in[4];
  const float* theta_b = (const float*)d_in[5];
  const float* phi_w   = (const float*)d_in[6];
  const float* phi_b   = (const float*)d_in[7];
  const float* W_w     = (const float*)d_in[8];
  const float* W_b     = (const float*)d_in[9];
  const float* bn_g    = (const float*)d_in[10];
  const float* bn_b    = (const float*)d_in[11];

  char* ws = (char*)d_ws;
  __hip_bfloat16* Theta = (__hip_bfloat16*)(ws);             // 4,718,592
  _Float16*       Gcm   = (_Float16*)(ws + 4718592);         // 1,179,648
  __hip_bfloat16* PhiT  = (__hip_bfloat16*)(ws + 5898240);   // 1,179,648
  float*          z2    = (float*)(ws + 7077888);            // 4,718,592
  float*          psum  = (float*)(ws + 11796480);           // 256

  conv_pool_k<<<dim3(144, NB), dim3(256), 0, stream>>>(
      x, feature, theta_w, theta_b, g_w, g_b, phi_w, phi_b, Theta, Gcm, PhiT, psum);
  attn_k<<<dim3(144, NB), dim3(256), 0, stream>>>(
      Theta, PhiT, Gcm, x, W_w, W_b, z2, psum);
  bn_apply<<<dim3(144, NB), dim3(256), 0, stream>>>(
      z2, psum, bn_g, bn_b, (float*)d_out);
}